// Round 4
// baseline (461.067 us; speedup 1.0000x reference)
//
#include <hip/hip_runtime.h>
#include <hip/hip_cooperative_groups.h>
#include <math.h>

namespace cg = cooperative_groups;

#define G 256
#define M 256
#define NNODES (G*M)
#define EDGES (NNODES*16)   // 1,048,576
#define C 3
#define K 5
#define D 128
#define GM (G*M)            // 65536

// Workspace layout (floats):
#define OFF_U0   0
#define OFF_MK0  196608
#define OFF_U1   393216
#define OFF_A0   589824
#define OFF_AK0  655360
#define OFF_A1   720896
#define OFF_MST  786432
#define OFF_AST  787200
#define ZERO_FLOATS 787456          // regions above zeroed in phase 0
#define NB 1024                     // blocks
#define NT 256                      // threads/block
#define OFF_PINFO 787456            // per-block partials (written unconditionally)
#define OFF_PL2   (OFF_PINFO + NB)
#define OFF_PPATH (OFF_PL2 + NB)    // C*G = 768
#define WS_FLOATS (OFF_PPATH + C*G)

__device__ __forceinline__ float waveReduceSum(float v) {
    #pragma unroll
    for (int o = 32; o > 0; o >>= 1) v += __shfl_xor(v, o, 64);
    return v;
}
__device__ __forceinline__ float waveReduceMax(float v) {
    #pragma unroll
    for (int o = 32; o > 0; o >>= 1) v = fmaxf(v, __shfl_xor(v, o, 64));
    return v;
}

// ---------------- Fused cooperative kernel ----------------
__global__ __launch_bounds__(NT, 4) void fusedK(
        const float* __restrict__ sij, const int* __restrict__ ei,
        const int* __restrict__ s, const int* __restrict__ t,
        const float* __restrict__ hg, const float* __restrict__ Hm,
        const float* __restrict__ pw, float* __restrict__ out,
        float* __restrict__ ws) {
    cg::grid_group grid = cg::this_grid();
    const int b = blockIdx.x, tx = threadIdx.x;
    const int tid = b * NT + tx;

    __shared__ int   sS[G], sT[G];
    __shared__ float sc[2][K], att[2][K];
    __shared__ float r0[4], r1[4], r2[4];

    // ---- Phase 0: zero accumulators; stage s/t in LDS; emb on blocks<384 ----
    for (int i = tid; i < ZERO_FLOATS; i += NB * NT) ws[i] = 0.f;
    sS[tx] = s[tx];
    sT[tx] = t[tx];

    if (b < 384) {
        int half = tx >> 7;                    // 0 or 1
        int d = tx & 127;
        int pair = b * 2 + half;               // c*G + g
        int c = pair / G, g = pair - c * G;
        float h = hg[g * D + d];
        if (d < K) sc[half][d] = 0.f;
        __syncthreads();
        #pragma unroll
        for (int k = 0; k < K; ++k) {
            float p = h * Hm[(c * K + k) * D + d];
            p = waveReduceSum(p);
            if ((tx & 63) == 0) atomicAdd(&sc[half][k], p);
        }
        __syncthreads();
        if (d == 0) {
            float m = sc[half][0];
            #pragma unroll
            for (int k = 1; k < K; ++k) m = fmaxf(m, sc[half][k]);
            float sum = 0.f, ex[K];
            #pragma unroll
            for (int k = 0; k < K; ++k) { ex[k] = __expf(sc[half][k] - m); sum += ex[k]; }
            #pragma unroll
            for (int k = 0; k < K; ++k) att[half][k] = ex[k] / sum;
        }
        __syncthreads();
        float o = 0.f;
        #pragma unroll
        for (int k = 0; k < K; ++k) o += att[half][k] * Hm[(c * K + k) * D + d];
        out[pair * D + d] = o;
    }
    __syncthreads();
    grid.sync();

    // ---- Phase A: edge scatter of row-s / col-t slices + info/l2 partials ----
    {
        float* u0  = ws + OFF_U0;
        float* mk0 = ws + OFF_MK0;
        float* a0  = ws + OFF_A0;
        float* ak0 = ws + OFF_AK0;
        float* Mst = ws + OFF_MST;
        float* Ast = ws + OFF_AST;

        int e0 = tid * 4;
        int4 src4 = *(const int4*)(ei + e0);
        int4 dst4 = *(const int4*)(ei + EDGES + e0);
        float4 v0 = *(const float4*)(sij + 0 * EDGES + e0);
        float4 v1 = *(const float4*)(sij + 1 * EDGES + e0);
        float4 v2 = *(const float4*)(sij + 2 * EDGES + e0);
        const int* srcp = (const int*)&src4;
        const int* dstp = (const int*)&dst4;
        const float* v0p = (const float*)&v0;
        const float* v1p = (const float*)&v1;
        const float* v2p = (const float*)&v2;

        float info = 0.f, l2 = 0.f;
        #pragma unroll
        for (int j = 0; j < 4; ++j) {
            int src = srcp[j], dst = dstp[j];
            int g = src >> 8;
            int r = src & 255;
            int c = dst - (g << 8);
            float v[C] = { v0p[j], v1p[j], v2p[j] };
            if (r == sS[g]) {
                #pragma unroll
                for (int cc = 0; cc < C; ++cc) atomicAdd(&u0[cc * GM + (g << 8) + c], v[cc]);
                atomicAdd(&a0[(g << 8) + c], 1.0f);
                if (c == sT[g]) {
                    #pragma unroll
                    for (int cc = 0; cc < C; ++cc) atomicAdd(&Mst[cc * G + g], v[cc]);
                    atomicAdd(&Ast[g], 1.0f);
                }
            }
            if (c == sT[g]) {
                #pragma unroll
                for (int cc = 0; cc < C; ++cc) atomicAdd(&mk0[cc * GM + (g << 8) + r], v[cc]);
                atomicAdd(&ak0[(g << 8) + r], 1.0f);
            }
            #pragma unroll
            for (int cc = 0; cc < C; ++cc) {
                float x = v[cc];
                info += x * __logf(x * 2.0f + 1e-6f)
                      + (1.0f - x) * __logf((1.0f - x) / 0.500001f + 1e-6f);
                l2 += x * x;
            }
        }
        info = waveReduceSum(info);
        l2 = waveReduceSum(l2);
        int wid = tx >> 6, lane = tx & 63;
        if (lane == 0) { r0[wid] = info; r1[wid] = l2; }
        __syncthreads();
        if (tx == 0) {
            float i2 = 0.f, l = 0.f;
            #pragma unroll
            for (int w = 0; w < 4; ++w) { i2 += r0[w]; l += r1[w]; }
            ws[OFF_PINFO + b] = i2;
            ws[OFF_PL2 + b] = l;
        }
    }
    grid.sync();

    // ---- Phase B: u1 = u0 @ Mdj (per class), a1 = a0 @ Adj, edge-wise ----
    {
        const float* u0 = ws + OFF_U0;
        const float* a0 = ws + OFF_A0;
        float* u1 = ws + OFF_U1;
        float* a1 = ws + OFF_A1;

        int e0 = tid * 4;
        int4 src4 = *(const int4*)(ei + e0);
        int4 dst4 = *(const int4*)(ei + EDGES + e0);
        const int* srcp = (const int*)&src4;
        const int* dstp = (const int*)&dst4;

        #pragma unroll
        for (int j = 0; j < 4; ++j) {
            int src = srcp[j], dst = dstp[j];
            int g = src >> 8;
            int r = src & 255;
            int c = dst - (g << 8);
            float ar = a0[(g << 8) + r];
            if (ar == 0.0f) continue;   // u0[g][r]==0 too (sij>0)
            atomicAdd(&a1[(g << 8) + c], ar);
            int e = e0 + j;
            #pragma unroll
            for (int cc = 0; cc < C; ++cc) {
                float ur = u0[cc * GM + (g << 8) + r];
                atomicAdd(&u1[cc * GM + (g << 8) + c], ur * sij[cc * EDGES + e]);
            }
        }
    }
    grid.sync();

    // ---- Phase path: blocks < 768 handle one (c,g) each ----
    if (b < C * G) {
        int c = b / G, g = b - c * G;
        const float* u0  = ws + OFF_U0;
        const float* mk0 = ws + OFF_MK0;
        const float* u1  = ws + OFF_U1;
        const float* a0  = ws + OFF_A0;
        const float* ak0 = ws + OFF_AK0;
        const float* a1  = ws + OFF_A1;

        int gi  = (g << 8) + tx;
        int cgi = c * GM + gi;
        float ak = ak0[gi], mk = mk0[cgi];
        float den0 = a0[gi] * ak;  den0 = (den0 == 0.f) ? 1e-8f : den0;
        float t0 = u0[cgi] * mk / den0;
        float den1 = a1[gi] * ak;  den1 = (den1 == 0.f) ? 1e-8f : den1;
        float t1 = u1[cgi] * mk / den1;

        t0 = waveReduceMax(t0);
        t1 = waveReduceMax(t1);
        int wid = tx >> 6, lane = tx & 63;
        if (lane == 0) { r0[wid] = t0; r1[wid] = t1; }
        __syncthreads();
        if (tx == 0) {
            float m0 = r0[0], m1 = r1[0];
            #pragma unroll
            for (int w = 1; w < 4; ++w) { m0 = fmaxf(m0, r0[w]); m1 = fmaxf(m1, r1[w]); }
            float w1 = fminf(fmaxf(pw[1], 1e-10f), 1.0f);
            float w2 = fminf(fmaxf(pw[2], 1e-10f), 1.0f);
            float A = ws[OFF_AST + g];  A = (A == 0.f) ? 1e-8f : A;
            float uk = ws[OFF_MST + c * G + g] / A;   // l+1=1 -> identity power
            uk += w1 * (m0 + 1e-8f);
            uk += w2 * sqrtf(m1 + 1e-8f);             // exponent 1/2 -> sqrt
            uk *= (1.0f / 3.0f);                      // / MAXLEN
            ws[OFF_PPATH + b] = __logf(uk + 1e-8f);
        }
    }
    grid.sync();

    // ---- Final: block 0 reduces all partials -> 3 scalars ----
    if (b == 0) {
        float info = 0.f, l2 = 0.f, path = 0.f;
        for (int i = tx; i < NB; i += NT) {
            info += ws[OFF_PINFO + i];
            l2   += ws[OFF_PL2 + i];
        }
        for (int i = tx; i < C * G; i += NT) path += ws[OFF_PPATH + i];
        info = waveReduceSum(info);
        l2   = waveReduceSum(l2);
        path = waveReduceSum(path);
        int wid = tx >> 6, lane = tx & 63;
        if (lane == 0) { r0[wid] = info; r1[wid] = l2; r2[wid] = path; }
        __syncthreads();
        if (tx == 0) {
            float i2 = 0.f, l = 0.f, p = 0.f;
            #pragma unroll
            for (int w = 0; w < 4; ++w) { i2 += r0[w]; l += r1[w]; p += r2[w]; }
            out[C * G * D + 0] = i2 / (float)(C * EDGES);            // L_info mean
            out[C * G * D + 1] = -p / (float)(C * G);                // L_path mean
            out[C * G * D + 2] = l / (2.0f * (float)G * (float)C);   // L_l2 mean
        }
    }
}

// ---------------- Fallback path (round-3 kernels) ----------------
__global__ void passA(const float* __restrict__ sij, const int* __restrict__ ei,
                      const int* __restrict__ s, const int* __restrict__ t,
                      const float* __restrict__ hg, const float* __restrict__ H,
                      float* __restrict__ out, float* __restrict__ ws) {
    __shared__ float sc[2][K];
    __shared__ float att[2][K];
    __shared__ float sInfo[4], sL2[4];

    if (blockIdx.x >= NB) {
        int half = threadIdx.x >> 7;
        int d = threadIdx.x & 127;
        int pair = (blockIdx.x - NB) * 2 + half;
        int c = pair / G, g = pair - c * G;
        float h = hg[g * D + d];
        if (d < K) sc[half][d] = 0.f;
        __syncthreads();
        #pragma unroll
        for (int k = 0; k < K; ++k) {
            float p = h * H[(c * K + k) * D + d];
            p = waveReduceSum(p);
            if ((threadIdx.x & 63) == 0) atomicAdd(&sc[half][k], p);
        }
        __syncthreads();
        if (d == 0) {
            float m = sc[half][0];
            #pragma unroll
            for (int k = 1; k < K; ++k) m = fmaxf(m, sc[half][k]);
            float sum = 0.f, ex[K];
            #pragma unroll
            for (int k = 0; k < K; ++k) { ex[k] = expf(sc[half][k] - m); sum += ex[k]; }
            #pragma unroll
            for (int k = 0; k < K; ++k) att[half][k] = ex[k] / sum;
        }
        __syncthreads();
        float o = 0.f;
        #pragma unroll
        for (int k = 0; k < K; ++k) o += att[half][k] * H[(c * K + k) * D + d];
        out[pair * D + d] = o;
        return;
    }

    float* u0  = ws + OFF_U0;
    float* mk0 = ws + OFF_MK0;
    float* a0  = ws + OFF_A0;
    float* ak0 = ws + OFF_AK0;
    float* Mst = ws + OFF_MST;
    float* Ast = ws + OFF_AST;

    int tid = blockIdx.x * 256 + threadIdx.x;
    int e0 = tid * 4;
    int4 src4 = *(const int4*)(ei + e0);
    int4 dst4 = *(const int4*)(ei + EDGES + e0);
    float4 v0 = *(const float4*)(sij + 0 * EDGES + e0);
    float4 v1 = *(const float4*)(sij + 1 * EDGES + e0);
    float4 v2 = *(const float4*)(sij + 2 * EDGES + e0);
    const int* srcp = (const int*)&src4;
    const int* dstp = (const int*)&dst4;
    const float* v0p = (const float*)&v0;
    const float* v1p = (const float*)&v1;
    const float* v2p = (const float*)&v2;

    float info = 0.f, l2 = 0.f;
    #pragma unroll
    for (int j = 0; j < 4; ++j) {
        int src = srcp[j], dst = dstp[j];
        int g = src >> 8;
        int r = src & 255;
        int c = dst - (g << 8);
        int sg = s[g], tg = t[g];
        float v[C] = { v0p[j], v1p[j], v2p[j] };
        if (r == sg) {
            #pragma unroll
            for (int cc = 0; cc < C; ++cc) atomicAdd(&u0[cc * GM + (g << 8) + c], v[cc]);
            atomicAdd(&a0[(g << 8) + c], 1.0f);
            if (c == tg) {
                #pragma unroll
                for (int cc = 0; cc < C; ++cc) atomicAdd(&Mst[cc * G + g], v[cc]);
                atomicAdd(&Ast[g], 1.0f);
            }
        }
        if (c == tg) {
            #pragma unroll
            for (int cc = 0; cc < C; ++cc) atomicAdd(&mk0[cc * GM + (g << 8) + r], v[cc]);
            atomicAdd(&ak0[(g << 8) + r], 1.0f);
        }
        #pragma unroll
        for (int cc = 0; cc < C; ++cc) {
            float x = v[cc];
            info += x * __logf(x * 2.0f + 1e-6f)
                  + (1.0f - x) * __logf((1.0f - x) / 0.500001f + 1e-6f);
            l2 += x * x;
        }
    }
    info = waveReduceSum(info);
    l2 = waveReduceSum(l2);
    int wid = threadIdx.x >> 6, lane = threadIdx.x & 63;
    if (lane == 0) { sInfo[wid] = info; sL2[wid] = l2; }
    __syncthreads();
    if (threadIdx.x == 0) {
        float i2 = 0.f, l = 0.f;
        #pragma unroll
        for (int w = 0; w < 4; ++w) { i2 += sInfo[w]; l += sL2[w]; }
        ws[OFF_PINFO + blockIdx.x] = i2;
        ws[OFF_PL2 + blockIdx.x] = l;
    }
}

__global__ void passB(const float* __restrict__ sij, const int* __restrict__ ei,
                      float* __restrict__ ws) {
    const float* u0 = ws + OFF_U0;
    const float* a0 = ws + OFF_A0;
    float* u1 = ws + OFF_U1;
    float* a1 = ws + OFF_A1;

    int tid = blockIdx.x * 256 + threadIdx.x;
    int e0 = tid * 4;
    int4 src4 = *(const int4*)(ei + e0);
    int4 dst4 = *(const int4*)(ei + EDGES + e0);
    const int* srcp = (const int*)&src4;
    const int* dstp = (const int*)&dst4;

    #pragma unroll
    for (int j = 0; j < 4; ++j) {
        int src = srcp[j], dst = dstp[j];
        int g = src >> 8;
        int r = src & 255;
        int c = dst - (g << 8);
        float ar = a0[(g << 8) + r];
        if (ar == 0.0f) continue;
        atomicAdd(&a1[(g << 8) + c], ar);
        int e = e0 + j;
        #pragma unroll
        for (int cc = 0; cc < C; ++cc) {
            float ur = u0[cc * GM + (g << 8) + r];
            atomicAdd(&u1[cc * GM + (g << 8) + c], ur * sij[cc * EDGES + e]);
        }
    }
}

__global__ void pathK(const float* __restrict__ pw, float* __restrict__ ws) {
    int b = blockIdx.x;
    int c = b / G, g = b - c * G;
    int x = threadIdx.x;
    const float* u0  = ws + OFF_U0;
    const float* mk0 = ws + OFF_MK0;
    const float* u1  = ws + OFF_U1;
    const float* a0  = ws + OFF_A0;
    const float* ak0 = ws + OFF_AK0;
    const float* a1  = ws + OFF_A1;

    int gi  = (g << 8) + x;
    int cgi = c * GM + gi;
    float ak = ak0[gi], mk = mk0[cgi];
    float den0 = a0[gi] * ak;  den0 = (den0 == 0.f) ? 1e-8f : den0;
    float t0 = u0[cgi] * mk / den0;
    float den1 = a1[gi] * ak;  den1 = (den1 == 0.f) ? 1e-8f : den1;
    float t1 = u1[cgi] * mk / den1;

    t0 = waveReduceMax(t0);
    t1 = waveReduceMax(t1);
    __shared__ float s0[4], s1[4];
    int wid = threadIdx.x >> 6, lane = threadIdx.x & 63;
    if (lane == 0) { s0[wid] = t0; s1[wid] = t1; }
    __syncthreads();
    if (threadIdx.x == 0) {
        float m0 = s0[0], m1 = s1[0];
        #pragma unroll
        for (int w = 1; w < 4; ++w) { m0 = fmaxf(m0, s0[w]); m1 = fmaxf(m1, s1[w]); }
        float w1 = fminf(fmaxf(pw[1], 1e-10f), 1.0f);
        float w2 = fminf(fmaxf(pw[2], 1e-10f), 1.0f);
        float A = ws[OFF_AST + g];  A = (A == 0.f) ? 1e-8f : A;
        float uk = ws[OFF_MST + c * G + g] / A;
        uk += w1 * (m0 + 1e-8f);
        uk += w2 * sqrtf(m1 + 1e-8f);
        uk *= (1.0f / 3.0f);
        ws[OFF_PPATH + b] = __logf(uk + 1e-8f);
    }
}

__global__ void finalK(const float* __restrict__ ws, float* __restrict__ out) {
    int tid = threadIdx.x;
    float info = 0.f, l2 = 0.f, path = 0.f;
    for (int i = tid; i < NB; i += 256) {
        info += ws[OFF_PINFO + i];
        l2   += ws[OFF_PL2 + i];
    }
    for (int i = tid; i < C * G; i += 256) path += ws[OFF_PPATH + i];
    info = waveReduceSum(info);
    l2   = waveReduceSum(l2);
    path = waveReduceSum(path);
    __shared__ float sI[4], sL[4], sP[4];
    int wid = tid >> 6, lane = tid & 63;
    if (lane == 0) { sI[wid] = info; sL[wid] = l2; sP[wid] = path; }
    __syncthreads();
    if (tid == 0) {
        float i2 = 0.f, l = 0.f, p = 0.f;
        #pragma unroll
        for (int w = 0; w < 4; ++w) { i2 += sI[w]; l += sL[w]; p += sP[w]; }
        out[C * G * D + 0] = i2 / (float)(C * EDGES);
        out[C * G * D + 1] = -p / (float)(C * G);
        out[C * G * D + 2] = l / (2.0f * (float)G * (float)C);
    }
}

extern "C" void kernel_launch(void* const* d_in, const int* in_sizes, int n_in,
                              void* d_out, int out_size, void* d_ws, size_t ws_size,
                              hipStream_t stream) {
    const float* hg  = (const float*)d_in[0];
    const float* Hm  = (const float*)d_in[1];
    const float* pw  = (const float*)d_in[2];
    const float* sij = (const float*)d_in[3];
    const int*   ei  = (const int*)d_in[4];
    // d_in[5] = batch (unused: batch[src] == src >> 8)
    const int*   s   = (const int*)d_in[6];
    const int*   t   = (const int*)d_in[7];
    float* out = (float*)d_out;
    float* ws  = (float*)d_ws;

    void* args[] = { (void*)&sij, (void*)&ei, (void*)&s, (void*)&t,
                     (void*)&hg, (void*)&Hm, (void*)&pw, (void*)&out, (void*)&ws };
    hipError_t err = hipLaunchCooperativeKernel((const void*)fusedK,
                                                dim3(NB), dim3(NT), args, 0, stream);
    if (err != hipSuccess) {
        // Fallback: 5-node pipeline (round-3 structure)
        hipMemsetAsync(d_ws, 0, ZERO_FLOATS * sizeof(float), stream);
        passA<<<NB + 384, 256, 0, stream>>>(sij, ei, s, t, hg, Hm, out, ws);
        passB<<<NB, 256, 0, stream>>>(sij, ei, ws);
        pathK<<<C * G, M, 0, stream>>>(pw, ws);
        finalK<<<1, 256, 0, stream>>>(ws, out);
    }
}

// Round 5
// 57.963 us; speedup vs baseline: 7.9545x; 7.9545x over previous
//
#include <hip/hip_runtime.h>
#include <math.h>

#define G 256
#define M 256
#define NNODES (G*M)
#define EDGES (NNODES*16)   // 1,048,576
#define C 3
#define K 5
#define D 128
#define GM (G*M)            // 65536

// Workspace layout (floats):
#define OFF_U0   0
#define OFF_MK0  196608
#define OFF_U1   393216
#define OFF_A0   589824
#define OFF_AK0  655360
#define OFF_A1   720896
#define OFF_MST  786432
#define OFF_AST  787200
#define OFF_CNT  787456             // int "blocks done" counter for pathFinal
#define ZERO_FLOATS 787457          // regions above zeroed by the memset node
// per-block partials (written unconditionally each call, no zeroing needed)
#define NB_EDGE  1024               // edge blocks (256 thr x 4 edges)
#define NB_EMB   384                // emb blocks appended to passA grid
#define OFF_PINFO 787457
#define OFF_PL2   (OFF_PINFO + NB_EDGE)
#define OFF_PPATH (OFF_PL2 + NB_EDGE)  // C*G = 768
#define WS_FLOATS (OFF_PPATH + C*G)

__device__ __forceinline__ float waveReduceSum(float v) {
    #pragma unroll
    for (int o = 32; o > 0; o >>= 1) v += __shfl_xor(v, o, 64);
    return v;
}
__device__ __forceinline__ float waveReduceMax(float v) {
    #pragma unroll
    for (int o = 32; o > 0; o >>= 1) v = fmaxf(v, __shfl_xor(v, o, 64));
    return v;
}

// Pass A (blocks 0..NB_EDGE-1): scatter row-s / col-t slices of Mdj & Adj,
// fused L_info/L_l2 partial sums. 4 edges/thread, vectorized loads, s/t in LDS.
// Blocks NB_EDGE.. : H_emb (independent work, hidden under passA).
__global__ void passA(const float* __restrict__ sij, const int* __restrict__ ei,
                      const int* __restrict__ s, const int* __restrict__ t,
                      const float* __restrict__ hg, const float* __restrict__ Hm,
                      float* __restrict__ out, float* __restrict__ ws) {
    __shared__ int   sS[G], sT[G];
    __shared__ float sc[2][K];
    __shared__ float att[2][K];
    __shared__ float sInfo[4], sL2[4];

    if (blockIdx.x >= NB_EDGE) {
        // ---- H_emb: 2 (c,g) pairs per block, 128 threads each ----
        int half = threadIdx.x >> 7;           // 0 or 1
        int d = threadIdx.x & 127;
        int pair = (blockIdx.x - NB_EDGE) * 2 + half;   // c*G + g
        int c = pair / G, g = pair - c * G;
        float h = hg[g * D + d];
        if (d < K) sc[half][d] = 0.f;
        __syncthreads();
        #pragma unroll
        for (int k = 0; k < K; ++k) {
            float p = h * Hm[(c * K + k) * D + d];
            p = waveReduceSum(p);
            if ((threadIdx.x & 63) == 0) atomicAdd(&sc[half][k], p);
        }
        __syncthreads();
        if (d == 0) {
            float m = sc[half][0];
            #pragma unroll
            for (int k = 1; k < K; ++k) m = fmaxf(m, sc[half][k]);
            float sum = 0.f, ex[K];
            #pragma unroll
            for (int k = 0; k < K; ++k) { ex[k] = __expf(sc[half][k] - m); sum += ex[k]; }
            #pragma unroll
            for (int k = 0; k < K; ++k) att[half][k] = ex[k] / sum;
        }
        __syncthreads();
        float o = 0.f;
        #pragma unroll
        for (int k = 0; k < K; ++k) o += att[half][k] * Hm[(c * K + k) * D + d];
        out[pair * D + d] = o;
        return;
    }

    // ---- edge pass ----
    sS[threadIdx.x] = s[threadIdx.x];
    sT[threadIdx.x] = t[threadIdx.x];
    __syncthreads();

    float* u0  = ws + OFF_U0;
    float* mk0 = ws + OFF_MK0;
    float* a0  = ws + OFF_A0;
    float* ak0 = ws + OFF_AK0;
    float* Mst = ws + OFF_MST;
    float* Ast = ws + OFF_AST;

    int tid = blockIdx.x * 256 + threadIdx.x;   // 0..262143
    int e0 = tid * 4;
    int4 src4 = *(const int4*)(ei + e0);
    int4 dst4 = *(const int4*)(ei + EDGES + e0);
    float4 v0 = *(const float4*)(sij + 0 * EDGES + e0);
    float4 v1 = *(const float4*)(sij + 1 * EDGES + e0);
    float4 v2 = *(const float4*)(sij + 2 * EDGES + e0);

    const int* srcp = (const int*)&src4;
    const int* dstp = (const int*)&dst4;
    const float* v0p = (const float*)&v0;
    const float* v1p = (const float*)&v1;
    const float* v2p = (const float*)&v2;

    float info = 0.f, l2 = 0.f;
    #pragma unroll
    for (int j = 0; j < 4; ++j) {
        int src = srcp[j], dst = dstp[j];
        int g = src >> 8;
        int r = src & 255;
        int c = dst - (g << 8);
        float v[C] = { v0p[j], v1p[j], v2p[j] };
        if (r == sS[g]) {
            #pragma unroll
            for (int cc = 0; cc < C; ++cc) atomicAdd(&u0[cc * GM + (g << 8) + c], v[cc]);
            atomicAdd(&a0[(g << 8) + c], 1.0f);
            if (c == sT[g]) {
                #pragma unroll
                for (int cc = 0; cc < C; ++cc) atomicAdd(&Mst[cc * G + g], v[cc]);
                atomicAdd(&Ast[g], 1.0f);
            }
        }
        if (c == sT[g]) {
            #pragma unroll
            for (int cc = 0; cc < C; ++cc) atomicAdd(&mk0[cc * GM + (g << 8) + r], v[cc]);
            atomicAdd(&ak0[(g << 8) + r], 1.0f);
        }
        #pragma unroll
        for (int cc = 0; cc < C; ++cc) {
            float x = v[cc];
            info += x * __logf(x * 2.0f + 1e-6f)
                  + (1.0f - x) * __logf((1.0f - x) / 0.500001f + 1e-6f);
            l2 += x * x;
        }
    }
    info = waveReduceSum(info);
    l2 = waveReduceSum(l2);
    int wid = threadIdx.x >> 6, lane = threadIdx.x & 63;
    if (lane == 0) { sInfo[wid] = info; sL2[wid] = l2; }
    __syncthreads();
    if (threadIdx.x == 0) {
        float i2 = 0.f, l = 0.f;
        #pragma unroll
        for (int w = 0; w < 4; ++w) { i2 += sInfo[w]; l += sL2[w]; }
        ws[OFF_PINFO + blockIdx.x] = i2;
        ws[OFF_PL2 + blockIdx.x] = l;
    }
}

// Pass B: u1 = u0 @ Mdj (per class), a1 = a0 @ Adj, edge-wise, 4 edges/thread.
__global__ void passB(const float* __restrict__ sij, const int* __restrict__ ei,
                      float* __restrict__ ws) {
    const float* u0 = ws + OFF_U0;
    const float* a0 = ws + OFF_A0;
    float* u1 = ws + OFF_U1;
    float* a1 = ws + OFF_A1;

    int tid = blockIdx.x * 256 + threadIdx.x;
    int e0 = tid * 4;
    int4 src4 = *(const int4*)(ei + e0);
    int4 dst4 = *(const int4*)(ei + EDGES + e0);
    const int* srcp = (const int*)&src4;
    const int* dstp = (const int*)&dst4;

    #pragma unroll
    for (int j = 0; j < 4; ++j) {
        int src = srcp[j], dst = dstp[j];
        int g = src >> 8;
        int r = src & 255;
        int c = dst - (g << 8);
        float ar = a0[(g << 8) + r];
        if (ar == 0.0f) continue;   // u0[g][r]==0 too (sij>0)
        atomicAdd(&a1[(g << 8) + c], ar);
        int e = e0 + j;
        #pragma unroll
        for (int cc = 0; cc < C; ++cc) {
            float ur = u0[cc * GM + (g << 8) + r];
            atomicAdd(&u1[cc * GM + (g << 8) + c], ur * sij[cc * EDGES + e]);
        }
    }
}

// Path loss finalize + final scalar reduce, fused via last-block-done pattern.
// 768 blocks: each computes one (c,g) max -> ws[OFF_PPATH+b]; the LAST block
// to finish additionally reduces all partials into the 3 scalar outputs.
__global__ void pathFinal(const float* __restrict__ pw, float* __restrict__ ws,
                          float* __restrict__ out) {
    int b = blockIdx.x;          // c*G + g
    int c = b / G, g = b - c * G;
    int x = threadIdx.x;         // 256 threads
    const float* u0  = ws + OFF_U0;
    const float* mk0 = ws + OFF_MK0;
    const float* u1  = ws + OFF_U1;
    const float* a0  = ws + OFF_A0;
    const float* ak0 = ws + OFF_AK0;
    const float* a1  = ws + OFF_A1;
    __shared__ float s0[4], s1[4], s2[4];
    __shared__ int isLast;

    int gi  = (g << 8) + x;
    int cgi = c * GM + gi;
    float ak = ak0[gi], mk = mk0[cgi];
    float den0 = a0[gi] * ak;  den0 = (den0 == 0.f) ? 1e-8f : den0;
    float t0 = u0[cgi] * mk / den0;
    float den1 = a1[gi] * ak;  den1 = (den1 == 0.f) ? 1e-8f : den1;
    float t1 = u1[cgi] * mk / den1;

    t0 = waveReduceMax(t0);
    t1 = waveReduceMax(t1);
    int wid = x >> 6, lane = x & 63;
    if (lane == 0) { s0[wid] = t0; s1[wid] = t1; }
    __syncthreads();
    if (x == 0) {
        float m0 = s0[0], m1 = s1[0];
        #pragma unroll
        for (int w = 1; w < 4; ++w) { m0 = fmaxf(m0, s0[w]); m1 = fmaxf(m1, s1[w]); }
        float w1 = fminf(fmaxf(pw[1], 1e-10f), 1.0f);
        float w2 = fminf(fmaxf(pw[2], 1e-10f), 1.0f);
        float A = ws[OFF_AST + g];  A = (A == 0.f) ? 1e-8f : A;
        float uk = ws[OFF_MST + c * G + g] / A;   // l+1=1 -> identity power
        uk += w1 * (m0 + 1e-8f);
        uk += w2 * sqrtf(m1 + 1e-8f);             // exponent 1/2 -> sqrt
        uk *= (1.0f / 3.0f);                      // / MAXLEN
        ws[OFF_PPATH + b] = __logf(uk + 1e-8f);
        __threadfence();                          // publish before signaling
        int done = atomicAdd((int*)(ws + OFF_CNT), 1);
        isLast = (done == C * G - 1);
    }
    __syncthreads();
    if (!isLast) return;
    __threadfence();   // acquire side: all 768 partials now visible

    // ---- final reduce (one block) ----
    float info = 0.f, l2 = 0.f, path = 0.f;
    for (int i = x; i < NB_EDGE; i += 256) {
        info += ws[OFF_PINFO + i];
        l2   += ws[OFF_PL2 + i];
    }
    for (int i = x; i < C * G; i += 256) path += ws[OFF_PPATH + i];
    info = waveReduceSum(info);
    l2   = waveReduceSum(l2);
    path = waveReduceSum(path);
    if (lane == 0) { s0[wid] = info; s1[wid] = l2; s2[wid] = path; }
    __syncthreads();
    if (x == 0) {
        float i2 = 0.f, l = 0.f, p = 0.f;
        #pragma unroll
        for (int w = 0; w < 4; ++w) { i2 += s0[w]; l += s1[w]; p += s2[w]; }
        out[C * G * D + 0] = i2 / (float)(C * EDGES);            // L_info mean
        out[C * G * D + 1] = -p / (float)(C * G);                // L_path mean
        out[C * G * D + 2] = l / (2.0f * (float)G * (float)C);   // L_l2 mean
    }
}

extern "C" void kernel_launch(void* const* d_in, const int* in_sizes, int n_in,
                              void* d_out, int out_size, void* d_ws, size_t ws_size,
                              hipStream_t stream) {
    const float* hg  = (const float*)d_in[0];
    const float* Hm  = (const float*)d_in[1];
    const float* pw  = (const float*)d_in[2];
    const float* sij = (const float*)d_in[3];
    const int*   ei  = (const int*)d_in[4];
    // d_in[5] = batch (unused: batch[src] == src >> 8)
    const int*   s   = (const int*)d_in[6];
    const int*   t   = (const int*)d_in[7];
    float* out = (float*)d_out;
    float* ws  = (float*)d_ws;

    hipMemsetAsync(d_ws, 0, ZERO_FLOATS * sizeof(float), stream);
    passA<<<NB_EDGE + NB_EMB, 256, 0, stream>>>(sij, ei, s, t, hg, Hm, out, ws);
    passB<<<NB_EDGE, 256, 0, stream>>>(sij, ei, ws);
    pathFinal<<<C * G, M, 0, stream>>>(pw, ws, out);
}

// Round 6
// 42.052 us; speedup vs baseline: 10.9643x; 1.3784x over previous
//
#include <hip/hip_runtime.h>
#include <math.h>

#define G 256
#define M 256
#define NNODES (G*M)
#define EDGES (NNODES*16)   // 1,048,576
#define C 3
#define K 5
#define D 128
#define GM (G*M)            // 65536

// Workspace layout (floats):
#define OFF_U0   0
#define OFF_MK0  196608
#define OFF_U1   393216
#define OFF_A0   589824
#define OFF_AK0  655360
#define OFF_A1   720896
#define OFF_MST  786432
#define OFF_AST  787200
#define ZERO_FLOATS 787456          // 3,149,824 B — MULTIPLE OF 16 (fill fast path!)
// per-block partials (written unconditionally each call, no zeroing needed)
#define NB_EDGE  512                // edge blocks (256 thr x 8 edges)
#define NB_EMB   384                // emb blocks appended to passA grid
#define OFF_PINFO 787456
#define OFF_PL2   (OFF_PINFO + NB_EDGE)
#define OFF_PPATH (OFF_PL2 + NB_EDGE)  // C*G = 768
#define WS_FLOATS (OFF_PPATH + C*G)

__device__ __forceinline__ float waveReduceSum(float v) {
    #pragma unroll
    for (int o = 32; o > 0; o >>= 1) v += __shfl_xor(v, o, 64);
    return v;
}
__device__ __forceinline__ float waveReduceMax(float v) {
    #pragma unroll
    for (int o = 32; o > 0; o >>= 1) v = fmaxf(v, __shfl_xor(v, o, 64));
    return v;
}

// Pass A (blocks 0..NB_EDGE-1): scatter row-s / col-t slices of Mdj & Adj,
// fused L_info/L_l2 partial sums. 8 edges/thread, vectorized loads, s/t in LDS.
// Blocks NB_EDGE.. : H_emb (independent work, hidden under passA).
__global__ void passA(const float* __restrict__ sij, const int* __restrict__ ei,
                      const int* __restrict__ s, const int* __restrict__ t,
                      const float* __restrict__ hg, const float* __restrict__ Hm,
                      float* __restrict__ out, float* __restrict__ ws) {
    __shared__ int   sS[G], sT[G];
    __shared__ float sc[2][K];
    __shared__ float att[2][K];
    __shared__ float sInfo[4], sL2[4];

    if (blockIdx.x >= NB_EDGE) {
        // ---- H_emb: 2 (c,g) pairs per block, 128 threads each ----
        int half = threadIdx.x >> 7;           // 0 or 1
        int d = threadIdx.x & 127;
        int pair = (blockIdx.x - NB_EDGE) * 2 + half;   // c*G + g
        int c = pair / G, g = pair - c * G;
        float h = hg[g * D + d];
        if (d < K) sc[half][d] = 0.f;
        __syncthreads();
        #pragma unroll
        for (int k = 0; k < K; ++k) {
            float p = h * Hm[(c * K + k) * D + d];
            p = waveReduceSum(p);
            if ((threadIdx.x & 63) == 0) atomicAdd(&sc[half][k], p);
        }
        __syncthreads();
        if (d == 0) {
            float m = sc[half][0];
            #pragma unroll
            for (int k = 1; k < K; ++k) m = fmaxf(m, sc[half][k]);
            float sum = 0.f, ex[K];
            #pragma unroll
            for (int k = 0; k < K; ++k) { ex[k] = __expf(sc[half][k] - m); sum += ex[k]; }
            #pragma unroll
            for (int k = 0; k < K; ++k) att[half][k] = ex[k] / sum;
        }
        __syncthreads();
        float o = 0.f;
        #pragma unroll
        for (int k = 0; k < K; ++k) o += att[half][k] * Hm[(c * K + k) * D + d];
        out[pair * D + d] = o;
        return;
    }

    // ---- edge pass ----
    sS[threadIdx.x] = s[threadIdx.x];
    sT[threadIdx.x] = t[threadIdx.x];
    __syncthreads();

    float* u0  = ws + OFF_U0;
    float* mk0 = ws + OFF_MK0;
    float* a0  = ws + OFF_A0;
    float* ak0 = ws + OFF_AK0;
    float* Mst = ws + OFF_MST;
    float* Ast = ws + OFF_AST;

    int tid = blockIdx.x * 256 + threadIdx.x;   // 0..131071
    int e0 = tid * 8;
    int4 srcA = *(const int4*)(ei + e0);
    int4 srcB = *(const int4*)(ei + e0 + 4);
    int4 dstA = *(const int4*)(ei + EDGES + e0);
    int4 dstB = *(const int4*)(ei + EDGES + e0 + 4);
    float4 v0a = *(const float4*)(sij + 0 * EDGES + e0);
    float4 v0b = *(const float4*)(sij + 0 * EDGES + e0 + 4);
    float4 v1a = *(const float4*)(sij + 1 * EDGES + e0);
    float4 v1b = *(const float4*)(sij + 1 * EDGES + e0 + 4);
    float4 v2a = *(const float4*)(sij + 2 * EDGES + e0);
    float4 v2b = *(const float4*)(sij + 2 * EDGES + e0 + 4);

    int srcp[8], dstp[8];
    float vp[3][8];
    *(int4*)&srcp[0] = srcA;  *(int4*)&srcp[4] = srcB;
    *(int4*)&dstp[0] = dstA;  *(int4*)&dstp[4] = dstB;
    *(float4*)&vp[0][0] = v0a; *(float4*)&vp[0][4] = v0b;
    *(float4*)&vp[1][0] = v1a; *(float4*)&vp[1][4] = v1b;
    *(float4*)&vp[2][0] = v2a; *(float4*)&vp[2][4] = v2b;

    float info = 0.f, l2 = 0.f;
    #pragma unroll
    for (int j = 0; j < 8; ++j) {
        int src = srcp[j], dst = dstp[j];
        int g = src >> 8;
        int r = src & 255;
        int c = dst - (g << 8);
        float v[C] = { vp[0][j], vp[1][j], vp[2][j] };
        if (r == sS[g]) {
            #pragma unroll
            for (int cc = 0; cc < C; ++cc) atomicAdd(&u0[cc * GM + (g << 8) + c], v[cc]);
            atomicAdd(&a0[(g << 8) + c], 1.0f);
            if (c == sT[g]) {
                #pragma unroll
                for (int cc = 0; cc < C; ++cc) atomicAdd(&Mst[cc * G + g], v[cc]);
                atomicAdd(&Ast[g], 1.0f);
            }
        }
        if (c == sT[g]) {
            #pragma unroll
            for (int cc = 0; cc < C; ++cc) atomicAdd(&mk0[cc * GM + (g << 8) + r], v[cc]);
            atomicAdd(&ak0[(g << 8) + r], 1.0f);
        }
        #pragma unroll
        for (int cc = 0; cc < C; ++cc) {
            float x = v[cc];
            info += x * __logf(x * 2.0f + 1e-6f)
                  + (1.0f - x) * __logf((1.0f - x) / 0.500001f + 1e-6f);
            l2 += x * x;
        }
    }
    info = waveReduceSum(info);
    l2 = waveReduceSum(l2);
    int wid = threadIdx.x >> 6, lane = threadIdx.x & 63;
    if (lane == 0) { sInfo[wid] = info; sL2[wid] = l2; }
    __syncthreads();
    if (threadIdx.x == 0) {
        float i2 = 0.f, l = 0.f;
        #pragma unroll
        for (int w = 0; w < 4; ++w) { i2 += sInfo[w]; l += sL2[w]; }
        ws[OFF_PINFO + blockIdx.x] = i2;
        ws[OFF_PL2 + blockIdx.x] = l;
    }
}

// Pass B: u1 = u0 @ Mdj (per class), a1 = a0 @ Adj, edge-wise, 8 edges/thread.
__global__ void passB(const float* __restrict__ sij, const int* __restrict__ ei,
                      float* __restrict__ ws) {
    const float* u0 = ws + OFF_U0;
    const float* a0 = ws + OFF_A0;
    float* u1 = ws + OFF_U1;
    float* a1 = ws + OFF_A1;

    int tid = blockIdx.x * 256 + threadIdx.x;
    int e0 = tid * 8;
    int4 srcA = *(const int4*)(ei + e0);
    int4 srcB = *(const int4*)(ei + e0 + 4);
    int4 dstA = *(const int4*)(ei + EDGES + e0);
    int4 dstB = *(const int4*)(ei + EDGES + e0 + 4);
    int srcp[8], dstp[8];
    *(int4*)&srcp[0] = srcA;  *(int4*)&srcp[4] = srcB;
    *(int4*)&dstp[0] = dstA;  *(int4*)&dstp[4] = dstB;

    #pragma unroll
    for (int j = 0; j < 8; ++j) {
        int src = srcp[j], dst = dstp[j];
        int g = src >> 8;
        int r = src & 255;
        int c = dst - (g << 8);
        float ar = a0[(g << 8) + r];
        if (ar == 0.0f) continue;   // u0[g][r]==0 too (sij>0)
        atomicAdd(&a1[(g << 8) + c], ar);
        int e = e0 + j;
        #pragma unroll
        for (int cc = 0; cc < C; ++cc) {
            float ur = u0[cc * GM + (g << 8) + r];
            atomicAdd(&u1[cc * GM + (g << 8) + c], ur * sij[cc * EDGES + e]);
        }
    }
}

// Path loss finalize: per (c,g) block max over M -> per-block log stored.
__global__ void pathK(const float* __restrict__ pw, float* __restrict__ ws) {
    int b = blockIdx.x;          // c*G + g
    int c = b / G, g = b - c * G;
    int x = threadIdx.x;         // 256 threads
    const float* u0  = ws + OFF_U0;
    const float* mk0 = ws + OFF_MK0;
    const float* u1  = ws + OFF_U1;
    const float* a0  = ws + OFF_A0;
    const float* ak0 = ws + OFF_AK0;
    const float* a1  = ws + OFF_A1;

    int gi  = (g << 8) + x;
    int cgi = c * GM + gi;
    float ak = ak0[gi], mk = mk0[cgi];
    float den0 = a0[gi] * ak;  den0 = (den0 == 0.f) ? 1e-8f : den0;
    float t0 = u0[cgi] * mk / den0;
    float den1 = a1[gi] * ak;  den1 = (den1 == 0.f) ? 1e-8f : den1;
    float t1 = u1[cgi] * mk / den1;

    t0 = waveReduceMax(t0);
    t1 = waveReduceMax(t1);
    __shared__ float s0[4], s1[4];
    int wid = x >> 6, lane = x & 63;
    if (lane == 0) { s0[wid] = t0; s1[wid] = t1; }
    __syncthreads();
    if (x == 0) {
        float m0 = s0[0], m1 = s1[0];
        #pragma unroll
        for (int w = 1; w < 4; ++w) { m0 = fmaxf(m0, s0[w]); m1 = fmaxf(m1, s1[w]); }
        float w1 = fminf(fmaxf(pw[1], 1e-10f), 1.0f);
        float w2 = fminf(fmaxf(pw[2], 1e-10f), 1.0f);
        float A = ws[OFF_AST + g];  A = (A == 0.f) ? 1e-8f : A;
        float uk = ws[OFF_MST + c * G + g] / A;   // l+1=1 -> identity power
        uk += w1 * (m0 + 1e-8f);
        uk += w2 * sqrtf(m1 + 1e-8f);             // exponent 1/2 -> sqrt
        uk *= (1.0f / 3.0f);                      // / MAXLEN
        ws[OFF_PPATH + b] = __logf(uk + 1e-8f);
    }
}

// Final reduce of all per-block partials -> 3 scalar outputs. One block.
__global__ void finalK(const float* __restrict__ ws, float* __restrict__ out) {
    int tid = threadIdx.x;       // 256 threads
    float info = 0.f, l2 = 0.f, path = 0.f;
    for (int i = tid; i < NB_EDGE; i += 256) {
        info += ws[OFF_PINFO + i];
        l2   += ws[OFF_PL2 + i];
    }
    for (int i = tid; i < C * G; i += 256) path += ws[OFF_PPATH + i];
    info = waveReduceSum(info);
    l2   = waveReduceSum(l2);
    path = waveReduceSum(path);
    __shared__ float sI[4], sL[4], sP[4];
    int wid = tid >> 6, lane = tid & 63;
    if (lane == 0) { sI[wid] = info; sL[wid] = l2; sP[wid] = path; }
    __syncthreads();
    if (tid == 0) {
        float i2 = 0.f, l = 0.f, p = 0.f;
        #pragma unroll
        for (int w = 0; w < 4; ++w) { i2 += sI[w]; l += sL[w]; p += sP[w]; }
        out[C * G * D + 0] = i2 / (float)(C * EDGES);            // L_info mean
        out[C * G * D + 1] = -p / (float)(C * G);                // L_path mean
        out[C * G * D + 2] = l / (2.0f * (float)G * (float)C);   // L_l2 mean
    }
}

extern "C" void kernel_launch(void* const* d_in, const int* in_sizes, int n_in,
                              void* d_out, int out_size, void* d_ws, size_t ws_size,
                              hipStream_t stream) {
    const float* hg  = (const float*)d_in[0];
    const float* Hm  = (const float*)d_in[1];
    const float* pw  = (const float*)d_in[2];
    const float* sij = (const float*)d_in[3];
    const int*   ei  = (const int*)d_in[4];
    // d_in[5] = batch (unused: batch[src] == src >> 8)
    const int*   s   = (const int*)d_in[6];
    const int*   t   = (const int*)d_in[7];
    float* out = (float*)d_out;
    float* ws  = (float*)d_ws;

    // 3,149,824 bytes — multiple of 16 so the runtime fill stays on the
    // dwordx4 fast path (round-5 lesson: +4B tail => 78 GB/s slow fill).
    hipMemsetAsync(d_ws, 0, ZERO_FLOATS * sizeof(float), stream);
    passA<<<NB_EDGE + NB_EMB, 256, 0, stream>>>(sij, ei, s, t, hg, Hm, out, ws);
    passB<<<NB_EDGE, 256, 0, stream>>>(sij, ei, ws);
    pathK<<<C * G, M, 0, stream>>>(pw, ws);
    finalK<<<1, 256, 0, stream>>>(ws, out);
}